// Round 1
// baseline (289.053 us; speedup 1.0000x reference)
//
#include <hip/hip_runtime.h>
#include <hip/hip_bf16.h>

// Problem constants (B=2, S=2048, D=1024, H=16, dk=64)
#define S_LEN   2048
#define D_MODEL 1024
#define NH      16
#define DKH     64
#define BATCH   2
#define BS_ROWS 4096   // B*S

typedef unsigned short u16;
typedef __attribute__((ext_vector_type(4))) float f32x4;
typedef __attribute__((ext_vector_type(8))) short bf16x8;

__device__ __forceinline__ float bf2f(u16 u) {
  union { unsigned int i; float f; } v; v.i = ((unsigned int)u) << 16; return v.f;
}
__device__ __forceinline__ u16 f2bf(float f) {
  union { __hip_bfloat16 h; u16 u; } cv; cv.h = __float2bfloat16(f); return cv.u;
}
__device__ __forceinline__ f32x4 mfma16(bf16x8 a, bf16x8 b, f32x4 c) {
  return __builtin_amdgcn_mfma_f32_16x16x32_bf16(a, b, c, 0, 0, 0);
}
// async global->LDS, 16B per lane. lptr must be wave-uniform; HW adds lane*16.
__device__ __forceinline__ void gl_lds16(const u16* g, u16* l) {
  __builtin_amdgcn_global_load_lds(
      (const __attribute__((address_space(1))) void*)g,
      (__attribute__((address_space(3))) void*)l, 16, 0, 0);
}

// ---------------- fp32 -> bf16 convert (vectorized) ----------------
__global__ void cvt_kernel(const float* __restrict__ in, u16* __restrict__ out, int n4) {
  int i = blockIdx.x * blockDim.x + threadIdx.x;
  if (i < n4) {
    float4 v = reinterpret_cast<const float4*>(in)[i];
    ushort4 o;
    o.x = f2bf(v.x); o.y = f2bf(v.y); o.z = f2bf(v.z); o.w = f2bf(v.w);
    reinterpret_cast<ushort4*>(out)[i] = o;
  }
}

// ---------------- GEMM  C[m,n] = sum_k A[m,k]*B[n,k]  (B^T layout) ----------------
// 128x128 tile, BK=64, 4 waves (2x2 of 64x64), 16x16x32 bf16 MFMA.
// LDS staging via global_load_lds (linear dest) with XOR-swizzled SOURCE chunks;
// reads apply the same involution  chunk ^= (row&7)  -> conflict-free ds_read_b128.
#define BM 128
#define BN 128
#define BKK 64

__global__ __launch_bounds__(256) void gemm_bt(
    const u16* __restrict__ A,
    const u16* __restrict__ B0, const u16* __restrict__ B1, const u16* __restrict__ B2,
    u16* __restrict__ C0, u16* __restrict__ C1, u16* __restrict__ C2,
    float* __restrict__ Cf,
    int M, int N, int K, int out_f32)
{
  __shared__ __align__(16) u16 As[BM * BKK];
  __shared__ __align__(16) u16 Bs[BN * BKK];

  const int z = blockIdx.z;
  const u16* Bm = (z == 0) ? B0 : ((z == 1) ? B1 : B2);
  u16* Cb = (z == 0) ? C0 : ((z == 1) ? C1 : C2);

  const int tid = threadIdx.x;
  const int l = tid & 63, w = tid >> 6;
  const int lr = l & 15, lg = l >> 4;
  const int m0 = blockIdx.y * BM, n0 = blockIdx.x * BN;
  const int wr = w >> 1, wc = w & 1;

  f32x4 acc[4][4];
#pragma unroll
  for (int mi = 0; mi < 4; ++mi)
#pragma unroll
    for (int nj = 0; nj < 4; ++nj)
      acc[mi][nj] = (f32x4){0.f, 0.f, 0.f, 0.f};

  for (int k0 = 0; k0 < K; k0 += BKK) {
    __syncthreads();
    // stage A,B tiles: 1024 chunks (16B) each; 4 issues per wave per matrix
#pragma unroll
    for (int i = 0; i < 4; ++i) {
      int Dc = w * 256 + i * 64 + l;        // dest chunk (linear in LDS)
      int row = Dc >> 3;                    // 8 chunks per 128B row
      int c = (Dc & 7) ^ (row & 7);         // pre-swizzled source chunk
      gl_lds16(A  + (size_t)(m0 + row) * K + k0 + c * 8, As + (w * 256 + i * 64) * 8);
      gl_lds16(Bm + (size_t)(n0 + row) * K + k0 + c * 8, Bs + (w * 256 + i * 64) * 8);
    }
    __syncthreads();

    bf16x8 af[2][4], bfr[2][4];
#pragma unroll
    for (int kk = 0; kk < 2; ++kk)
#pragma unroll
      for (int mi = 0; mi < 4; ++mi) {
        int rowa = wr * 64 + mi * 16 + lr;
        int ck = kk * 4 + lg;
        af[kk][mi] = *(const bf16x8*)&As[rowa * BKK + (((ck) ^ (rowa & 7)) << 3)];
        int rowb = wc * 64 + mi * 16 + lr;
        bfr[kk][mi] = *(const bf16x8*)&Bs[rowb * BKK + (((ck) ^ (rowb & 7)) << 3)];
      }
#pragma unroll
    for (int kk = 0; kk < 2; ++kk)
#pragma unroll
      for (int mi = 0; mi < 4; ++mi)
#pragma unroll
        for (int nj = 0; nj < 4; ++nj)
          acc[mi][nj] = mfma16(af[kk][mi], bfr[kk][nj], acc[mi][nj]);
  }

  // epilogue: C/D layout col=lane&15, row=(lane>>4)*4+reg
#pragma unroll
  for (int mi = 0; mi < 4; ++mi)
#pragma unroll
    for (int nj = 0; nj < 4; ++nj)
#pragma unroll
      for (int r = 0; r < 4; ++r) {
        int row = m0 + wr * 64 + mi * 16 + lg * 4 + r;
        int col = n0 + wc * 64 + nj * 16 + lr;
        float v = acc[mi][nj][r];
        if (out_f32) Cf[(size_t)row * N + col] = v;
        else         Cb[(size_t)row * N + col] = f2bf(v);
      }
}

// ---------------- RoPE + relayout + scale ----------------
// Reads Yq/Yk/Yv bf16 [4096][1024]; writes Qb,Kb [B,H,S,dk] (Q scaled by 1/8),
// V transposed Vt [B,H,dk,S].
__global__ void rope_pack(const u16* __restrict__ Yq, const u16* __restrict__ Yk,
                          const u16* __restrict__ Yv, const int* __restrict__ pos,
                          u16* __restrict__ Qb, u16* __restrict__ Kb, u16* __restrict__ Vt)
{
  int t = blockIdx.x * blockDim.x + threadIdx.x;  // one thread per (row, pair)
  if (t >= BS_ROWS * (D_MODEL / 2)) return;
  int pi = t & 511;            // pair index in row: h*32 + j
  int r  = t >> 9;             // row = b*S + s
  int h = pi >> 5, j = pi & 31;
  int b = r >> 11, s = r & (S_LEN - 1);
  int p = pos[s];

  float freq = exp2f(-(float)j * 0.41524101186092028f);  // log2(10000)/32
  float ang = (float)p * freq;
  float sn, cs;
  sincosf(ang, &sn, &cs);

  int base = r * D_MODEL + pi * 2;
  float q0 = bf2f(Yq[base]), q1 = bf2f(Yq[base + 1]);
  float k0 = bf2f(Yk[base]), k1 = bf2f(Yk[base + 1]);
  float v0 = bf2f(Yv[base]), v1 = bf2f(Yv[base + 1]);

  float qr0 = (cs * q0 - sn * q1) * 0.125f;   // fold 1/sqrt(dk)
  float qr1 = (sn * q0 + cs * q1) * 0.125f;
  float kr0 = cs * k0 - sn * k1;
  float kr1 = sn * k0 + cs * k1;

  int bh = b * NH + h;
  size_t qidx = ((size_t)bh * S_LEN + s) * DKH + 2 * j;
  ushort2 qo; qo.x = f2bf(qr0); qo.y = f2bf(qr1);
  ushort2 ko; ko.x = f2bf(kr0); ko.y = f2bf(kr1);
  *reinterpret_cast<ushort2*>(Qb + qidx) = qo;
  *reinterpret_cast<ushort2*>(Kb + qidx) = ko;
  Vt[((size_t)bh * DKH + 2 * j)     * S_LEN + s] = f2bf(v0);
  Vt[((size_t)bh * DKH + 2 * j + 1) * S_LEN + s] = f2bf(v1);
}

// ---------------- causal flash attention ----------------
// grid: (32 qblocks, 32 b*h). 4 waves; wave w owns q rows [qb*64+w*16, +16).
// K tile [64 kv][64 d], Vt tile [64 d][64 kv] in LDS (swizzled); P via per-wave LDS.
__global__ __launch_bounds__(256) void attn_fwd(
    const u16* __restrict__ Qb, const u16* __restrict__ Kb,
    const u16* __restrict__ Vt, u16* __restrict__ Ob)
{
  const int qb = blockIdx.x, bh = blockIdx.y;
  const int b = bh >> 4, h = bh & 15;
  const int tid = threadIdx.x, l = tid & 63, w = tid >> 6;
  const int lr = l & 15, lg = l >> 4;

  __shared__ __align__(16) u16 Ks[64 * 64];
  __shared__ __align__(16) u16 Vs[64 * 64];
  __shared__ __align__(16) u16 Ps[4][16 * 64];

  const u16* Qh = Qb + (size_t)bh * S_LEN * DKH;
  const u16* Kh = Kb + (size_t)bh * S_LEN * DKH;
  const u16* Vh = Vt + (size_t)bh * DKH * S_LEN;

  const int q0 = qb * 64 + w * 16;

  bf16x8 qf[2];
#pragma unroll
  for (int kk = 0; kk < 2; ++kk)
    qf[kk] = *(const bf16x8*)(Qh + (size_t)(q0 + lr) * DKH + kk * 32 + lg * 8);

  f32x4 oacc[4];
#pragma unroll
  for (int nb = 0; nb < 4; ++nb) oacc[nb] = (f32x4){0.f, 0.f, 0.f, 0.f};
  float m[4], lsum[4];
#pragma unroll
  for (int r = 0; r < 4; ++r) { m[r] = -INFINITY; lsum[r] = 0.f; }

  const int nt = qb + 1;
  for (int t = 0; t < nt; ++t) {
    const int kv0 = t * 64;
    __syncthreads();
    // stage K tile (rows=kv, contiguous 128B) and Vt tile (rows=d, stride S)
#pragma unroll
    for (int i = 0; i < 2; ++i) {
      int Dc = w * 128 + i * 64 + l;
      int row = Dc >> 3;
      int c = (Dc & 7) ^ (row & 7);
      gl_lds16(Kh + (size_t)(kv0 + row) * DKH + c * 8, Ks + (w * 128 + i * 64) * 8);
      gl_lds16(Vh + (size_t)row * S_LEN + kv0 + c * 8, Vs + (w * 128 + i * 64) * 8);
    }
    __syncthreads();

    // S = Q K^T (scaled Q): sf[nj] covers kv cols nj*16+lr, rows lg*4+r
    f32x4 sf[4];
#pragma unroll
    for (int nj = 0; nj < 4; ++nj) {
      f32x4 a = (f32x4){0.f, 0.f, 0.f, 0.f};
#pragma unroll
      for (int kk = 0; kk < 2; ++kk) {
        int brow = nj * 16 + lr;
        bf16x8 kf = *(const bf16x8*)&Ks[brow * 64 + (((kk * 4 + lg) ^ (brow & 7)) << 3)];
        a = mfma16(qf[kk], kf, a);
      }
      sf[nj] = a;
    }
    // causal mask (only final tile can be partial)
    if (kv0 + 63 > q0) {
#pragma unroll
      for (int nj = 0; nj < 4; ++nj)
#pragma unroll
        for (int r = 0; r < 4; ++r) {
          int colg = kv0 + nj * 16 + lr;
          int rowg = q0 + lg * 4 + r;
          if (colg > rowg) sf[nj][r] = -1e30f;
        }
    }
    // online softmax (row-reduce across the 16 lanes holding this row's cols)
    float scale[4];
#pragma unroll
    for (int r = 0; r < 4; ++r) {
      float v = fmaxf(fmaxf(sf[0][r], sf[1][r]), fmaxf(sf[2][r], sf[3][r]));
      v = fmaxf(v, __shfl_xor(v, 1));
      v = fmaxf(v, __shfl_xor(v, 2));
      v = fmaxf(v, __shfl_xor(v, 4));
      v = fmaxf(v, __shfl_xor(v, 8));
      float mn = fmaxf(m[r], v);
      scale[r] = __expf(m[r] - mn);
      m[r] = mn;
    }
    float psum[4] = {0.f, 0.f, 0.f, 0.f};
#pragma unroll
    for (int nj = 0; nj < 4; ++nj)
#pragma unroll
      for (int r = 0; r < 4; ++r) {
        float p = __expf(sf[nj][r] - m[r]);
        sf[nj][r] = p;
        psum[r] += p;
      }
#pragma unroll
    for (int r = 0; r < 4; ++r) lsum[r] = lsum[r] * scale[r] + psum[r];
#pragma unroll
    for (int nb = 0; nb < 4; ++nb)
#pragma unroll
      for (int r = 0; r < 4; ++r) oacc[nb][r] *= scale[r];

    // P -> per-wave LDS (swizzled), then PV MFMAs. Same-wave DS ops are in-order.
#pragma unroll
    for (int nj = 0; nj < 4; ++nj)
#pragma unroll
      for (int r = 0; r < 4; ++r) {
        int row = lg * 4 + r, col = nj * 16 + lr;
        int ck = col >> 3;
        Ps[w][row * 64 + ((ck ^ (row & 7)) << 3) + (col & 7)] = f2bf(sf[nj][r]);
      }
#pragma unroll
    for (int kk = 0; kk < 2; ++kk) {
      bf16x8 pa = *(const bf16x8*)&Ps[w][lr * 64 + (((kk * 4 + lg) ^ (lr & 7)) << 3)];
#pragma unroll
      for (int nb = 0; nb < 4; ++nb) {
        int vrow = nb * 16 + lr;
        bf16x8 vf = *(const bf16x8*)&Vs[vrow * 64 + (((kk * 4 + lg) ^ (vrow & 7)) << 3)];
        oacc[nb] = mfma16(pa, vf, oacc[nb]);
      }
    }
  }

  // finalize: reduce lsum across the 16-lane col groups, normalize, store
#pragma unroll
  for (int r = 0; r < 4; ++r) {
    float v = lsum[r];
    v += __shfl_xor(v, 1); v += __shfl_xor(v, 2);
    v += __shfl_xor(v, 4); v += __shfl_xor(v, 8);
    lsum[r] = 1.0f / v;
  }
#pragma unroll
  for (int nb = 0; nb < 4; ++nb)
#pragma unroll
    for (int r = 0; r < 4; ++r) {
      int sg = q0 + lg * 4 + r;
      int dg = nb * 16 + lr;
      Ob[(size_t)b * S_LEN * D_MODEL + (size_t)sg * D_MODEL + h * DKH + dg] =
          f2bf(oacc[nb][r] * lsum[r]);
    }
}

// ---------------- launch ----------------
extern "C" void kernel_launch(void* const* d_in, const int* in_sizes, int n_in,
                              void* d_out, int out_size, void* d_ws, size_t ws_size,
                              hipStream_t stream) {
  const float* x   = (const float*)d_in[0];
  const int*   pos = (const int*)d_in[1];
  const float* WQ  = (const float*)d_in[2];
  const float* WK  = (const float*)d_in[3];
  const float* WV  = (const float*)d_in[4];
  const float* WO  = (const float*)d_in[5];

  char* ws = (char*)d_ws;
  u16* xb  = (u16*)(ws);                        // 8 MB  x bf16 [4096][1024]
  u16* wqb = (u16*)(ws + (size_t)(8)  * 1048576);
  u16* wkb = (u16*)(ws + (size_t)(10) * 1048576);
  u16* wvb = (u16*)(ws + (size_t)(12) * 1048576);
  u16* wob = (u16*)(ws + (size_t)(14) * 1048576);
  u16* Yq  = (u16*)(ws + (size_t)(16) * 1048576); // 8 MB each
  u16* Yk  = (u16*)(ws + (size_t)(24) * 1048576);
  u16* Yv  = (u16*)(ws + (size_t)(32) * 1048576);
  u16* Qb  = (u16*)(ws + (size_t)(40) * 1048576); // [B,H,S,dk]
  u16* Kb  = (u16*)(ws + (size_t)(48) * 1048576);
  u16* Vt  = (u16*)(ws + (size_t)(56) * 1048576); // [B,H,dk,S]
  u16* Ob  = (u16*)(ws + (size_t)(64) * 1048576); // [B,S,H,dk]

  // 1. convert inputs to bf16
  cvt_kernel<<<4096, 256, 0, stream>>>(x,  xb,  BS_ROWS * D_MODEL / 4);
  cvt_kernel<<<1024, 256, 0, stream>>>(WQ, wqb, D_MODEL * D_MODEL / 4);
  cvt_kernel<<<1024, 256, 0, stream>>>(WK, wkb, D_MODEL * D_MODEL / 4);
  cvt_kernel<<<1024, 256, 0, stream>>>(WV, wvb, D_MODEL * D_MODEL / 4);
  cvt_kernel<<<1024, 256, 0, stream>>>(WO, wob, D_MODEL * D_MODEL / 4);

  // 2. Q/K/V projections (batched over grid.z)
  gemm_bt<<<dim3(D_MODEL / BN, BS_ROWS / BM, 3), 256, 0, stream>>>(
      xb, wqb, wkb, wvb, Yq, Yk, Yv, nullptr, BS_ROWS, D_MODEL, D_MODEL, 0);

  // 3. RoPE + scale + relayout (+ V transpose)
  rope_pack<<<(BS_ROWS * (D_MODEL / 2)) / 256, 256, 0, stream>>>(
      Yq, Yk, Yv, pos, Qb, Kb, Vt);

  // 4. causal flash attention
  attn_fwd<<<dim3(S_LEN / 64, BATCH * NH), 256, 0, stream>>>(Qb, Kb, Vt, Ob);

  // 5. output projection -> fp32 d_out
  gemm_bt<<<dim3(D_MODEL / BN, BS_ROWS / BM, 1), 256, 0, stream>>>(
      Ob, wob, wob, wob, nullptr, nullptr, nullptr, (float*)d_out,
      BS_ROWS, D_MODEL, D_MODEL, 0 /*placeholder*/ + 1);
}

// Round 3
// 249.060 us; speedup vs baseline: 1.1606x; 1.1606x over previous
//
#include <hip/hip_runtime.h>
#include <hip/hip_bf16.h>

// Problem constants (B=2, S=2048, D=1024, H=16, dk=64)
#define S_LEN   2048
#define D_MODEL 1024
#define NH      16
#define DKH     64
#define BATCH   2
#define BS_ROWS 4096   // B*S

typedef unsigned short u16;
typedef __attribute__((ext_vector_type(4))) float f32x4;
typedef __attribute__((ext_vector_type(8))) short bf16x8;

__device__ __forceinline__ float bf2f(u16 u) {
  union { unsigned int i; float f; } v; v.i = ((unsigned int)u) << 16; return v.f;
}
__device__ __forceinline__ u16 f2bf(float f) {
  union { __hip_bfloat16 h; u16 u; } cv; cv.h = __float2bfloat16(f); return cv.u;
}
__device__ __forceinline__ f32x4 mfma16(bf16x8 a, bf16x8 b, f32x4 c) {
  return __builtin_amdgcn_mfma_f32_16x16x32_bf16(a, b, c, 0, 0, 0);
}
// async global->LDS, 16B per lane. LDS ptr wave-uniform; HW adds lane*16.
__device__ __forceinline__ void gl_lds16(const u16* g, u16* l) {
  __builtin_amdgcn_global_load_lds(
      (const __attribute__((address_space(1))) void*)g,
      (__attribute__((address_space(3))) void*)l, 16, 0, 0);
}

// ---------------- fp32 -> bf16 convert (single launch, 8 segments) ----------------
// seg 0..3: quarters of x (1M elems each); seg 4..7: WQ,WK,WV,WO (1M each)
__global__ void cvt_all(const float* __restrict__ x,
                        const float* __restrict__ wq, const float* __restrict__ wk,
                        const float* __restrict__ wv, const float* __restrict__ wo,
                        u16* __restrict__ xb, u16* __restrict__ wqb, u16* __restrict__ wkb,
                        u16* __restrict__ wvb, u16* __restrict__ wob) {
  int seg = blockIdx.y;
  const float* src; u16* dst;
  if (seg < 4)      { src = x + (size_t)seg * (1u << 20); dst = xb + (size_t)seg * (1u << 20); }
  else if (seg == 4){ src = wq; dst = wqb; }
  else if (seg == 5){ src = wk; dst = wkb; }
  else if (seg == 6){ src = wv; dst = wvb; }
  else              { src = wo; dst = wob; }
  int i = blockIdx.x * 256 + threadIdx.x;      // 262144 float4 per segment
  float4 v = reinterpret_cast<const float4*>(src)[i];
  ushort4 o;
  o.x = f2bf(v.x); o.y = f2bf(v.y); o.z = f2bf(v.z); o.w = f2bf(v.w);
  reinterpret_cast<ushort4*>(dst)[i] = o;
}

// ---------------- GEMM  C[m,n] = sum_k A[m,k]*B[n,k]  (B^T layout) ----------------
#define BM 128
#define BN 128
#define BKK 64

__global__ __launch_bounds__(256) void gemm_bt(
    const u16* __restrict__ A,
    const u16* __restrict__ B0, const u16* __restrict__ B1, const u16* __restrict__ B2,
    u16* __restrict__ C0, u16* __restrict__ C1, u16* __restrict__ C2,
    float* __restrict__ Cf,
    int M, int N, int K, int out_f32)
{
  __shared__ __align__(16) u16 As[BM * BKK];
  __shared__ __align__(16) u16 Bs[BN * BKK];

  const int z = blockIdx.z;
  const u16* Bm = (z == 0) ? B0 : ((z == 1) ? B1 : B2);
  u16* Cb = (z == 0) ? C0 : ((z == 1) ? C1 : C2);

  const int tid = threadIdx.x;
  const int l = tid & 63, w = tid >> 6;
  const int lr = l & 15, lg = l >> 4;
  const int m0 = blockIdx.y * BM, n0 = blockIdx.x * BN;
  const int wr = w >> 1, wc = w & 1;

  f32x4 acc[4][4];
#pragma unroll
  for (int mi = 0; mi < 4; ++mi)
#pragma unroll
    for (int nj = 0; nj < 4; ++nj)
      acc[mi][nj] = (f32x4){0.f, 0.f, 0.f, 0.f};

  for (int k0 = 0; k0 < K; k0 += BKK) {
    __syncthreads();
#pragma unroll
    for (int i = 0; i < 4; ++i) {
      int Dc = w * 256 + i * 64 + l;        // dest chunk (linear in LDS)
      int row = Dc >> 3;                    // 8 chunks per 128B row
      int c = (Dc & 7) ^ (row & 7);         // pre-swizzled source chunk
      gl_lds16(A  + (size_t)(m0 + row) * K + k0 + c * 8, As + (w * 256 + i * 64) * 8);
      gl_lds16(Bm + (size_t)(n0 + row) * K + k0 + c * 8, Bs + (w * 256 + i * 64) * 8);
    }
    __syncthreads();

    bf16x8 af[2][4], bfr[2][4];
#pragma unroll
    for (int kk = 0; kk < 2; ++kk)
#pragma unroll
      for (int mi = 0; mi < 4; ++mi) {
        int rowa = wr * 64 + mi * 16 + lr;
        int ck = kk * 4 + lg;
        af[kk][mi] = *(const bf16x8*)&As[rowa * BKK + (((ck) ^ (rowa & 7)) << 3)];
        int rowb = wc * 64 + mi * 16 + lr;
        bfr[kk][mi] = *(const bf16x8*)&Bs[rowb * BKK + (((ck) ^ (rowb & 7)) << 3)];
      }
#pragma unroll
    for (int kk = 0; kk < 2; ++kk)
#pragma unroll
      for (int mi = 0; mi < 4; ++mi)
#pragma unroll
        for (int nj = 0; nj < 4; ++nj)
          acc[mi][nj] = mfma16(af[kk][mi], bfr[kk][nj], acc[mi][nj]);
  }

  // epilogue: C/D layout col=lane&15, row=(lane>>4)*4+reg
#pragma unroll
  for (int mi = 0; mi < 4; ++mi)
#pragma unroll
    for (int nj = 0; nj < 4; ++nj)
#pragma unroll
      for (int r = 0; r < 4; ++r) {
        int row = m0 + wr * 64 + mi * 16 + lg * 4 + r;
        int col = n0 + wc * 64 + nj * 16 + lr;
        float v = acc[mi][nj][r];
        if (out_f32) Cf[(size_t)row * N + col] = v;
        else         Cb[(size_t)row * N + col] = f2bf(v);
      }
}

// ---------------- RoPE + relayout + scale ----------------
// Q gets 0.125 * log2(e) folded in (softmax runs in exp2 domain).
__global__ void rope_pack(const u16* __restrict__ Yq, const u16* __restrict__ Yk,
                          const u16* __restrict__ Yv, const int* __restrict__ pos,
                          u16* __restrict__ Qb, u16* __restrict__ Kb, u16* __restrict__ Vt)
{
  int t = blockIdx.x * blockDim.x + threadIdx.x;  // one thread per (row, pair)
  if (t >= BS_ROWS * (D_MODEL / 2)) return;
  int pi = t & 511;            // pair index in row: h*32 + j
  int r  = t >> 9;             // row = b*S + s
  int h = pi >> 5, j = pi & 31;
  int b = r >> 11, s = r & (S_LEN - 1);
  int p = pos[s];

  float freq = exp2f(-(float)j * 0.41524101186092028f);  // log2(10000)/32
  float ang = (float)p * freq;
  float sn, cs;
  sincosf(ang, &sn, &cs);

  int base = r * D_MODEL + pi * 2;
  float q0 = bf2f(Yq[base]), q1 = bf2f(Yq[base + 1]);
  float k0 = bf2f(Yk[base]), k1 = bf2f(Yk[base + 1]);
  float v0 = bf2f(Yv[base]), v1 = bf2f(Yv[base + 1]);

  const float QS = 0.18033688011112042f;  // 0.125 * log2(e)
  float qr0 = (cs * q0 - sn * q1) * QS;
  float qr1 = (sn * q0 + cs * q1) * QS;
  float kr0 = cs * k0 - sn * k1;
  float kr1 = sn * k0 + cs * k1;

  int bh = b * NH + h;
  size_t qidx = ((size_t)bh * S_LEN + s) * DKH + 2 * j;
  ushort2 qo; qo.x = f2bf(qr0); qo.y = f2bf(qr1);
  ushort2 ko; ko.x = f2bf(kr0); ko.y = f2bf(kr1);
  *reinterpret_cast<ushort2*>(Qb + qidx) = qo;
  *reinterpret_cast<ushort2*>(Kb + qidx) = ko;
  Vt[((size_t)bh * DKH + 2 * j)     * S_LEN + s] = f2bf(v0);
  Vt[((size_t)bh * DKH + 2 * j + 1) * S_LEN + s] = f2bf(v1);
}

// ---------------- causal flash attention (paired q-blocks, double-buffered) ---------
// 512 blocks: f = xcd + 8*(bh_local*16 + p); block handles q-blocks p and 31-p of
// its (b,h), sharing each staged K/V tile. Every block = exactly 33 tile-computes.
__global__ __launch_bounds__(256) void attn_fwd(
    const u16* __restrict__ Qb, const u16* __restrict__ Kb,
    const u16* __restrict__ Vt, u16* __restrict__ Ob)
{
  const int f = blockIdx.x;
  const int xcd = f & 7, slot = f >> 3;
  const int bh = xcd * 4 + (slot >> 4);      // 4 bh per XCD -> K/V L2-resident
  const int p  = slot & 15;
  const int qbh = 31 - p, qbl = p;           // hi and lo q-blocks (diagonal pair)
  const int b = bh >> 4, h = bh & 15;
  const int tid = threadIdx.x, l = tid & 63, w = tid >> 6;
  const int lr = l & 15, lg = l >> 4;

  __shared__ __align__(16) u16 Ks[2][64 * 64];
  __shared__ __align__(16) u16 Vs[2][64 * 64];
  __shared__ __align__(16) u16 Ps[4][16 * 64];

  const u16* Qh = Qb + (size_t)bh * S_LEN * DKH;
  const u16* Kh = Kb + (size_t)bh * S_LEN * DKH;
  const u16* Vh = Vt + (size_t)bh * DKH * S_LEN;

  const int q0h = qbh * 64 + w * 16;
  const int q0l = qbl * 64 + w * 16;

  bf16x8 qfh[2], qfl[2];
#pragma unroll
  for (int kk = 0; kk < 2; ++kk) {
    qfh[kk] = *(const bf16x8*)(Qh + (size_t)(q0h + lr) * DKH + kk * 32 + lg * 8);
    qfl[kk] = *(const bf16x8*)(Qh + (size_t)(q0l + lr) * DKH + kk * 32 + lg * 8);
  }

  f32x4 oh[4], ol[4];
  float mh[4], ml[4], lh[4], ll[4];
#pragma unroll
  for (int r = 0; r < 4; ++r) {
    mh[r] = -INFINITY; ml[r] = -INFINITY; lh[r] = 0.f; ll[r] = 0.f;
  }
#pragma unroll
  for (int nb = 0; nb < 4; ++nb) {
    oh[nb] = (f32x4){0.f, 0.f, 0.f, 0.f};
    ol[nb] = (f32x4){0.f, 0.f, 0.f, 0.f};
  }

#define STAGE(buf, tt) do {                                                        \
    int kv0s = (tt) * 64;                                                          \
    _Pragma("unroll")                                                              \
    for (int i = 0; i < 2; ++i) {                                                  \
      int Dc = w * 128 + i * 64 + l;                                               \
      int row = Dc >> 3;                                                           \
      int c = (Dc & 7) ^ (row & 7);                                                \
      gl_lds16(Kh + (size_t)(kv0s + row) * DKH + c * 8, &Ks[buf][(w * 128 + i * 64) * 8]); \
      gl_lds16(Vh + (size_t)row * S_LEN + kv0s + c * 8, &Vs[buf][(w * 128 + i * 64) * 8]); \
    }                                                                              \
  } while (0)

  // one tile-compute for one q-part against K/V buffer `cur` at kv offset kv0
  auto compute = [&](int cur, int kv0, const bf16x8 (&qf)[2], f32x4 (&oacc)[4],
                     float (&m)[4], float (&lsum)[4], int q0, bool diag) {
    f32x4 sf[4];
#pragma unroll
    for (int nj = 0; nj < 4; ++nj) {
      f32x4 a = (f32x4){0.f, 0.f, 0.f, 0.f};
#pragma unroll
      for (int kk = 0; kk < 2; ++kk) {
        int brow = nj * 16 + lr;
        bf16x8 kf = *(const bf16x8*)&Ks[cur][brow * 64 + (((kk * 4 + lg) ^ (brow & 7)) << 3)];
        a = mfma16(qf[kk], kf, a);
      }
      sf[nj] = a;
    }
    if (diag) {
#pragma unroll
      for (int nj = 0; nj < 4; ++nj)
#pragma unroll
        for (int r = 0; r < 4; ++r) {
          int colg = kv0 + nj * 16 + lr;
          int rowg = q0 + lg * 4 + r;
          if (colg > rowg) sf[nj][r] = -1e30f;
        }
    }
    // per-row max across the 16 lanes holding this row's cols
    float pm[4];
#pragma unroll
    for (int r = 0; r < 4; ++r) {
      float v = fmaxf(fmaxf(sf[0][r], sf[1][r]), fmaxf(sf[2][r], sf[3][r]));
      v = fmaxf(v, __shfl_xor(v, 1));
      v = fmaxf(v, __shfl_xor(v, 2));
      v = fmaxf(v, __shfl_xor(v, 4));
      v = fmaxf(v, __shfl_xor(v, 8));
      pm[r] = v;
    }
    // defer-max: only rescale when the running max grew by > 8 (log2 domain)
    bool need = false;
#pragma unroll
    for (int r = 0; r < 4; ++r) need = need || (pm[r] > m[r] + 8.f);
    if (__any(need)) {
#pragma unroll
      for (int r = 0; r < 4; ++r) {
        float mn = fmaxf(m[r], pm[r]);
        float sc = exp2f(m[r] - mn);
        m[r] = mn;
        lsum[r] *= sc;
#pragma unroll
        for (int nb = 0; nb < 4; ++nb) oacc[nb][r] *= sc;
      }
    }
    float ps[4] = {0.f, 0.f, 0.f, 0.f};
#pragma unroll
    for (int nj = 0; nj < 4; ++nj)
#pragma unroll
      for (int r = 0; r < 4; ++r) {
        float pv = exp2f(sf[nj][r] - m[r]);
        sf[nj][r] = pv;
        ps[r] += pv;
      }
#pragma unroll
    for (int r = 0; r < 4; ++r) lsum[r] += ps[r];

    // P -> per-wave LDS (swizzled), then PV MFMAs (same-wave DS ordering)
#pragma unroll
    for (int nj = 0; nj < 4; ++nj)
#pragma unroll
      for (int r = 0; r < 4; ++r) {
        int row = lg * 4 + r, col = nj * 16 + lr;
        int ck = col >> 3;
        Ps[w][row * 64 + ((ck ^ (row & 7)) << 3) + (col & 7)] = f2bf(sf[nj][r]);
      }
#pragma unroll
    for (int kk = 0; kk < 2; ++kk) {
      bf16x8 pa = *(const bf16x8*)&Ps[w][lr * 64 + (((kk * 4 + lg) ^ (lr & 7)) << 3)];
#pragma unroll
      for (int nb = 0; nb < 4; ++nb) {
        int vrow = nb * 16 + lr;
        bf16x8 vf = *(const bf16x8*)&Vs[cur][vrow * 64 + (((kk * 4 + lg) ^ (vrow & 7)) << 3)];
        oacc[nb] = mfma16(pa, vf, oacc[nb]);
      }
    }
  };

  const int nt = 32 - p;       // tiles for the hi part; lo part uses t <= p
  STAGE(0, 0);
  __syncthreads();
  int cur = 0;
  for (int t = 0; t < nt; ++t) {
    if (t + 1 < nt) STAGE(cur ^ 1, t + 1);
    const int kv0 = t * 64;
    compute(cur, kv0, qfh, oh, mh, lh, q0h, t == qbh);
    if (t <= p) compute(cur, kv0, qfl, ol, ml, ll, q0l, t == qbl);
    __syncthreads();           // drains prefetch vmcnt + syncs buffers
    cur ^= 1;
  }
#undef STAGE

  // finalize both parts
  auto finish = [&](f32x4 (&oacc)[4], float (&lsum)[4], int q0) {
    float inv[4];
#pragma unroll
    for (int r = 0; r < 4; ++r) {
      float v = lsum[r];
      v += __shfl_xor(v, 1); v += __shfl_xor(v, 2);
      v += __shfl_xor(v, 4); v += __shfl_xor(v, 8);
      inv[r] = 1.0f / v;
    }
#pragma unroll
    for (int nb = 0; nb < 4; ++nb)
#pragma unroll
      for (int r = 0; r < 4; ++r) {
        int sg = q0 + lg * 4 + r;
        int dg = nb * 16 + lr;
        Ob[(size_t)b * S_LEN * D_MODEL + (size_t)sg * D_MODEL + h * DKH + dg] =
            f2bf(oacc[nb][r] * inv[r]);
      }
  };
  finish(oh, lh, q0h);
  finish(ol, ll, q0l);
}

// ---------------- launch ----------------
extern "C" void kernel_launch(void* const* d_in, const int* in_sizes, int n_in,
                              void* d_out, int out_size, void* d_ws, size_t ws_size,
                              hipStream_t stream) {
  const float* x   = (const float*)d_in[0];
  const int*   pos = (const int*)d_in[1];
  const float* WQ  = (const float*)d_in[2];
  const float* WK  = (const float*)d_in[3];
  const float* WV  = (const float*)d_in[4];
  const float* WO  = (const float*)d_in[5];

  char* ws = (char*)d_ws;
  u16* xb  = (u16*)(ws);                          // 8 MB  x bf16 [4096][1024]
  u16* wqb = (u16*)(ws + (size_t)(8)  * 1048576);
  u16* wkb = (u16*)(ws + (size_t)(10) * 1048576);
  u16* wvb = (u16*)(ws + (size_t)(12) * 1048576);
  u16* wob = (u16*)(ws + (size_t)(14) * 1048576);
  u16* Yq  = (u16*)(ws + (size_t)(16) * 1048576); // 8 MB each
  u16* Yk  = (u16*)(ws + (size_t)(24) * 1048576);
  u16* Yv  = (u16*)(ws + (size_t)(32) * 1048576);
  u16* Qb  = (u16*)(ws + (size_t)(40) * 1048576); // [B,H,S,dk]
  u16* Kb  = (u16*)(ws + (size_t)(48) * 1048576);
  u16* Vt  = (u16*)(ws + (size_t)(56) * 1048576); // [B,H,dk,S]
  u16* Ob  = (u16*)(ws + (size_t)(64) * 1048576); // [B,S,H,dk]

  // 1. convert inputs to bf16 (single launch)
  cvt_all<<<dim3(1024, 8), 256, 0, stream>>>(x, WQ, WK, WV, WO, xb, wqb, wkb, wvb, wob);

  // 2. Q/K/V projections (batched over grid.z)
  gemm_bt<<<dim3(D_MODEL / BN, BS_ROWS / BM, 3), 256, 0, stream>>>(
      xb, wqb, wkb, wvb, Yq, Yk, Yv, nullptr, BS_ROWS, D_MODEL, D_MODEL, 0);

  // 3. RoPE + scale + relayout (+ V transpose)
  rope_pack<<<(BS_ROWS * (D_MODEL / 2)) / 256, 256, 0, stream>>>(
      Yq, Yk, Yv, pos, Qb, Kb, Vt);

  // 4. causal flash attention (paired q-blocks)
  attn_fwd<<<dim3(512), 256, 0, stream>>>(Qb, Kb, Vt, Ob);

  // 5. output projection -> fp32 d_out
  gemm_bt<<<dim3(D_MODEL / BN, BS_ROWS / BM, 1), 256, 0, stream>>>(
      Ob, wob, wob, wob, nullptr, nullptr, nullptr, (float*)d_out,
      BS_ROWS, D_MODEL, D_MODEL, 1);
}

// Round 4
// 238.196 us; speedup vs baseline: 1.2135x; 1.0456x over previous
//
#include <hip/hip_runtime.h>
#include <hip/hip_bf16.h>

// Problem constants (B=2, S=2048, D=1024, H=16, dk=64)
#define S_LEN   2048
#define D_MODEL 1024
#define NH      16
#define DKH     64
#define BATCH   2
#define BS_ROWS 4096   // B*S

typedef unsigned short u16;
typedef unsigned int   u32;
typedef __attribute__((ext_vector_type(4))) float f32x4;
typedef __attribute__((ext_vector_type(8))) short bf16x8;

__device__ __forceinline__ float bf2f(u16 u) {
  union { unsigned int i; float f; } v; v.i = ((unsigned int)u) << 16; return v.f;
}
__device__ __forceinline__ u16 f2bf(float f) {
  union { __hip_bfloat16 h; u16 u; } cv; cv.h = __float2bfloat16(f); return cv.u;
}
__device__ __forceinline__ f32x4 mfma16(bf16x8 a, bf16x8 b, f32x4 c) {
  return __builtin_amdgcn_mfma_f32_16x16x32_bf16(a, b, c, 0, 0, 0);
}
// async global->LDS, 16B per lane. LDS ptr wave-uniform; HW adds lane*16.
__device__ __forceinline__ void gl_lds16(const u16* g, u16* l) {
  __builtin_amdgcn_global_load_lds(
      (const __attribute__((address_space(1))) void*)g,
      (__attribute__((address_space(3))) void*)l, 16, 0, 0);
}

// ---------------- fp32 -> bf16 convert (single launch, 8 segments) ----------------
__global__ void cvt_all(const float* __restrict__ x,
                        const float* __restrict__ wq, const float* __restrict__ wk,
                        const float* __restrict__ wv, const float* __restrict__ wo,
                        u16* __restrict__ xb, u16* __restrict__ wqb, u16* __restrict__ wkb,
                        u16* __restrict__ wvb, u16* __restrict__ wob) {
  int seg = blockIdx.y;
  const float* src; u16* dst;
  if (seg < 4)      { src = x + (size_t)seg * (1u << 20); dst = xb + (size_t)seg * (1u << 20); }
  else if (seg == 4){ src = wq; dst = wqb; }
  else if (seg == 5){ src = wk; dst = wkb; }
  else if (seg == 6){ src = wv; dst = wvb; }
  else              { src = wo; dst = wob; }
  int i = blockIdx.x * 256 + threadIdx.x;      // 262144 float4 per segment
  float4 v = reinterpret_cast<const float4*>(src)[i];
  ushort4 o;
  o.x = f2bf(v.x); o.y = f2bf(v.y); o.z = f2bf(v.z); o.w = f2bf(v.w);
  reinterpret_cast<ushort4*>(dst)[i] = o;
}

// ---------------- GEMM  C[m,n] = sum_k A[m,k]*B[n,k]  (B^T layout) ----------------
#define BM 128
#define BN 128
#define BKK 64

__global__ __launch_bounds__(256) void gemm_bt(
    const u16* __restrict__ A,
    const u16* __restrict__ B0, const u16* __restrict__ B1, const u16* __restrict__ B2,
    u16* __restrict__ C0, u16* __restrict__ C1, u16* __restrict__ C2,
    float* __restrict__ Cf,
    int M, int N, int K, int out_f32)
{
  __shared__ __align__(16) u16 As[BM * BKK];
  __shared__ __align__(16) u16 Bs[BN * BKK];

  const int z = blockIdx.z;
  const u16* Bm = (z == 0) ? B0 : ((z == 1) ? B1 : B2);
  u16* Cb = (z == 0) ? C0 : ((z == 1) ? C1 : C2);

  const int tid = threadIdx.x;
  const int l = tid & 63, w = tid >> 6;
  const int lr = l & 15, lg = l >> 4;
  const int m0 = blockIdx.y * BM, n0 = blockIdx.x * BN;
  const int wr = w >> 1, wc = w & 1;

  f32x4 acc[4][4];
#pragma unroll
  for (int mi = 0; mi < 4; ++mi)
#pragma unroll
    for (int nj = 0; nj < 4; ++nj)
      acc[mi][nj] = (f32x4){0.f, 0.f, 0.f, 0.f};

  for (int k0 = 0; k0 < K; k0 += BKK) {
    __syncthreads();
#pragma unroll
    for (int i = 0; i < 4; ++i) {
      int Dc = w * 256 + i * 64 + l;        // dest chunk (linear in LDS)
      int row = Dc >> 3;                    // 8 chunks per 128B row
      int c = (Dc & 7) ^ (row & 7);         // pre-swizzled source chunk
      gl_lds16(A  + (size_t)(m0 + row) * K + k0 + c * 8, As + (w * 256 + i * 64) * 8);
      gl_lds16(Bm + (size_t)(n0 + row) * K + k0 + c * 8, Bs + (w * 256 + i * 64) * 8);
    }
    __syncthreads();

    bf16x8 af[2][4], bfr[2][4];
#pragma unroll
    for (int kk = 0; kk < 2; ++kk)
#pragma unroll
      for (int mi = 0; mi < 4; ++mi) {
        int rowa = wr * 64 + mi * 16 + lr;
        int ck = kk * 4 + lg;
        af[kk][mi] = *(const bf16x8*)&As[rowa * BKK + (((ck) ^ (rowa & 7)) << 3)];
        int rowb = wc * 64 + mi * 16 + lr;
        bfr[kk][mi] = *(const bf16x8*)&Bs[rowb * BKK + (((ck) ^ (rowb & 7)) << 3)];
      }
#pragma unroll
    for (int kk = 0; kk < 2; ++kk)
#pragma unroll
      for (int mi = 0; mi < 4; ++mi)
#pragma unroll
        for (int nj = 0; nj < 4; ++nj)
          acc[mi][nj] = mfma16(af[kk][mi], bfr[kk][nj], acc[mi][nj]);
  }

  // epilogue: C/D layout col=lane&15, row=(lane>>4)*4+reg
#pragma unroll
  for (int mi = 0; mi < 4; ++mi)
#pragma unroll
    for (int nj = 0; nj < 4; ++nj)
#pragma unroll
      for (int r = 0; r < 4; ++r) {
        int row = m0 + wr * 64 + mi * 16 + lg * 4 + r;
        int col = n0 + wc * 64 + nj * 16 + lr;
        float v = acc[mi][nj][r];
        if (out_f32) Cf[(size_t)row * N + col] = v;
        else         Cb[(size_t)row * N + col] = f2bf(v);
      }
}

// ---------------- RoPE (Q,K only) ----------------
// Q gets 0.125 * log2(e) folded in (softmax runs in exp2 domain).
__global__ void rope_pack(const u16* __restrict__ Yq, const u16* __restrict__ Yk,
                          const int* __restrict__ pos,
                          u16* __restrict__ Qb, u16* __restrict__ Kb)
{
  int t = blockIdx.x * blockDim.x + threadIdx.x;  // one thread per (row, pair)
  if (t >= BS_ROWS * (D_MODEL / 2)) return;
  int pi = t & 511;            // pair index in row: h*32 + j
  int r  = t >> 9;             // row = b*S + s
  int h = pi >> 5, j = pi & 31;
  int b = r >> 11, s = r & (S_LEN - 1);
  int p = pos[s];

  float freq = exp2f(-(float)j * 0.41524101186092028f);  // log2(10000)/32
  float ang = (float)p * freq;
  float sn, cs;
  sincosf(ang, &sn, &cs);

  int base = r * D_MODEL + pi * 2;
  float q0 = bf2f(Yq[base]), q1 = bf2f(Yq[base + 1]);
  float k0 = bf2f(Yk[base]), k1 = bf2f(Yk[base + 1]);

  const float QS = 0.18033688011112042f;  // 0.125 * log2(e)
  float qr0 = (cs * q0 - sn * q1) * QS;
  float qr1 = (sn * q0 + cs * q1) * QS;
  float kr0 = cs * k0 - sn * k1;
  float kr1 = sn * k0 + cs * k1;

  int bh = b * NH + h;
  size_t qidx = ((size_t)bh * S_LEN + s) * DKH + 2 * j;
  ushort2 qo; qo.x = f2bf(qr0); qo.y = f2bf(qr1);
  ushort2 ko; ko.x = f2bf(kr0); ko.y = f2bf(kr1);
  *reinterpret_cast<ushort2*>(Qb + qidx) = qo;
  *reinterpret_cast<ushort2*>(Kb + qidx) = ko;
}

// ---------------- V transpose:  Vt[bh][d][s] = Yv[b*S+s][h*64+d] ----------------
// LDS u32 tile [64][65]: both phases 2-way bank aliasing only (free);
// both global sides coalesced (128B runs).
__global__ __launch_bounds__(256) void transpose_v(const u16* __restrict__ Yv,
                                                   u16* __restrict__ Vt)
{
  __shared__ u32 T[64][65];
  const int sb = blockIdx.x;            // s-tile (0..31)
  const int bh = blockIdx.y;            // 0..31
  const int b = bh >> 4, h = bh & 15;
  const int t = threadIdx.x;
  const int s0 = sb * 64;

#pragma unroll
  for (int pass = 0; pass < 2; ++pass) {
    int row = pass * 32 + (t >> 3);     // 0..63
    int c0 = (t & 7) * 8;
    bf16x8 v = *(const bf16x8*)(Yv + (size_t)(b * S_LEN + s0 + row) * D_MODEL + h * DKH + c0);
#pragma unroll
    for (int i = 0; i < 8; ++i) T[row][c0 + i] = (u32)(u16)v[i];
  }
  __syncthreads();

  const int d = t >> 2, ch = t & 3;
  bf16x8 o0, o1;
#pragma unroll
  for (int i = 0; i < 8; ++i) o0[i] = (short)(u16)T[ch * 16 + i][d];
#pragma unroll
  for (int i = 0; i < 8; ++i) o1[i] = (short)(u16)T[ch * 16 + 8 + i][d];
  u16* dst = Vt + ((size_t)bh * DKH + d) * S_LEN + s0 + ch * 16;
  *(bf16x8*)dst = o0;
  *(bf16x8*)(dst + 8) = o1;
}

// ---------------- causal flash attention (unpaired, longest-first) ----------------
// 1024 blocks: qb = 31 - (f>>5) (longest first), bh = f&31 (bh%8 -> fixed XCD).
// 40KB LDS, VGPR capped for 4 blocks/CU = 4 waves/SIMD.
__global__ __launch_bounds__(256, 4) void attn_fwd(
    const u16* __restrict__ Qb, const u16* __restrict__ Kb,
    const u16* __restrict__ Vt, u16* __restrict__ Ob)
{
  const int f = blockIdx.x;
  const int qb = 31 - (f >> 5);
  const int bh = f & 31;
  const int b = bh >> 4, h = bh & 15;
  const int tid = threadIdx.x, l = tid & 63, w = tid >> 6;
  const int lr = l & 15, lg = l >> 4;

  __shared__ __align__(16) u16 Ks[2][64 * 64];
  __shared__ __align__(16) u16 Vs[2][64 * 64];
  __shared__ __align__(16) u16 Ps[4][16 * 64];

  const u16* Qh = Qb + (size_t)bh * S_LEN * DKH;
  const u16* Kh = Kb + (size_t)bh * S_LEN * DKH;
  const u16* Vh = Vt + (size_t)bh * DKH * S_LEN;

  const int q0 = qb * 64 + w * 16;

  bf16x8 qf[2];
#pragma unroll
  for (int kk = 0; kk < 2; ++kk)
    qf[kk] = *(const bf16x8*)(Qh + (size_t)(q0 + lr) * DKH + kk * 32 + lg * 8);

  f32x4 oacc[4];
  float m[4], lsum[4];
#pragma unroll
  for (int r = 0; r < 4; ++r) { m[r] = -INFINITY; lsum[r] = 0.f; }
#pragma unroll
  for (int nb = 0; nb < 4; ++nb) oacc[nb] = (f32x4){0.f, 0.f, 0.f, 0.f};

#define STAGE(buf, tt) do {                                                        \
    int kv0s = (tt) * 64;                                                          \
    _Pragma("unroll")                                                              \
    for (int i = 0; i < 2; ++i) {                                                  \
      int Dc = w * 128 + i * 64 + l;                                               \
      int row = Dc >> 3;                                                           \
      int c = (Dc & 7) ^ (row & 7);                                                \
      gl_lds16(Kh + (size_t)(kv0s + row) * DKH + c * 8, &Ks[buf][(w * 128 + i * 64) * 8]); \
      gl_lds16(Vh + (size_t)row * S_LEN + kv0s + c * 8, &Vs[buf][(w * 128 + i * 64) * 8]); \
    }                                                                              \
  } while (0)

  const int nt = qb + 1;
  STAGE(0, 0);
  __syncthreads();
  int cur = 0;
  for (int t = 0; t < nt; ++t) {
    if (t + 1 < nt) STAGE(cur ^ 1, t + 1);
    const int kv0 = t * 64;

    // S = Q K^T (scale + log2e folded into Q)
    f32x4 sf[4];
#pragma unroll
    for (int nj = 0; nj < 4; ++nj) {
      f32x4 a = (f32x4){0.f, 0.f, 0.f, 0.f};
#pragma unroll
      for (int kk = 0; kk < 2; ++kk) {
        int brow = nj * 16 + lr;
        bf16x8 kf = *(const bf16x8*)&Ks[cur][brow * 64 + (((kk * 4 + lg) ^ (brow & 7)) << 3)];
        a = mfma16(qf[kk], kf, a);
      }
      sf[nj] = a;
    }
    if (t == qb) {   // diagonal tile: causal mask
#pragma unroll
      for (int nj = 0; nj < 4; ++nj)
#pragma unroll
        for (int r = 0; r < 4; ++r) {
          int colg = kv0 + nj * 16 + lr;
          int rowg = q0 + lg * 4 + r;
          if (colg > rowg) sf[nj][r] = -1e30f;
        }
    }
    // per-row max over the 16 lanes holding this row's cols
    float pm[4];
#pragma unroll
    for (int r = 0; r < 4; ++r) {
      float v = fmaxf(fmaxf(sf[0][r], sf[1][r]), fmaxf(sf[2][r], sf[3][r]));
      v = fmaxf(v, __shfl_xor(v, 1));
      v = fmaxf(v, __shfl_xor(v, 2));
      v = fmaxf(v, __shfl_xor(v, 4));
      v = fmaxf(v, __shfl_xor(v, 8));
      pm[r] = v;
    }
    // defer-max: rescale only when the max grew by > 8 (log2 domain)
    bool need = false;
#pragma unroll
    for (int r = 0; r < 4; ++r) need = need || (pm[r] > m[r] + 8.f);
    if (__any(need)) {
#pragma unroll
      for (int r = 0; r < 4; ++r) {
        float mn = fmaxf(m[r], pm[r]);
        float sc = exp2f(m[r] - mn);
        m[r] = mn;
        lsum[r] *= sc;
#pragma unroll
        for (int nb = 0; nb < 4; ++nb) oacc[nb][r] *= sc;
      }
    }
    float ps[4] = {0.f, 0.f, 0.f, 0.f};
#pragma unroll
    for (int nj = 0; nj < 4; ++nj)
#pragma unroll
      for (int r = 0; r < 4; ++r) {
        float pv = exp2f(sf[nj][r] - m[r]);
        sf[nj][r] = pv;
        ps[r] += pv;
      }
#pragma unroll
    for (int r = 0; r < 4; ++r) lsum[r] += ps[r];

    // P -> per-wave LDS (swizzled), then PV MFMAs (same-wave DS ordering)
#pragma unroll
    for (int nj = 0; nj < 4; ++nj)
#pragma unroll
      for (int r = 0; r < 4; ++r) {
        int row = lg * 4 + r, col = nj * 16 + lr;
        int ck = col >> 3;
        Ps[w][row * 64 + ((ck ^ (row & 7)) << 3) + (col & 7)] = f2bf(sf[nj][r]);
      }
#pragma unroll
    for (int kk = 0; kk < 2; ++kk) {
      bf16x8 pa = *(const bf16x8*)&Ps[w][lr * 64 + (((kk * 4 + lg) ^ (lr & 7)) << 3)];
#pragma unroll
      for (int nb = 0; nb < 4; ++nb) {
        int vrow = nb * 16 + lr;
        bf16x8 vf = *(const bf16x8*)&Vs[cur][vrow * 64 + (((kk * 4 + lg) ^ (vrow & 7)) << 3)];
        oacc[nb] = mfma16(pa, vf, oacc[nb]);
      }
    }

    __syncthreads();           // drains prefetch vmcnt + buffer swap
    cur ^= 1;
  }
#undef STAGE

  // finalize
  float inv[4];
#pragma unroll
  for (int r = 0; r < 4; ++r) {
    float v = lsum[r];
    v += __shfl_xor(v, 1); v += __shfl_xor(v, 2);
    v += __shfl_xor(v, 4); v += __shfl_xor(v, 8);
    inv[r] = 1.0f / v;
  }
#pragma unroll
  for (int nb = 0; nb < 4; ++nb)
#pragma unroll
    for (int r = 0; r < 4; ++r) {
      int sg = q0 + lg * 4 + r;
      int dg = nb * 16 + lr;
      Ob[(size_t)b * S_LEN * D_MODEL + (size_t)sg * D_MODEL + h * DKH + dg] =
          f2bf(oacc[nb][r] * inv[r]);
    }
}

// ---------------- launch ----------------
extern "C" void kernel_launch(void* const* d_in, const int* in_sizes, int n_in,
                              void* d_out, int out_size, void* d_ws, size_t ws_size,
                              hipStream_t stream) {
  const float* x   = (const float*)d_in[0];
  const int*   pos = (const int*)d_in[1];
  const float* WQ  = (const float*)d_in[2];
  const float* WK  = (const float*)d_in[3];
  const float* WV  = (const float*)d_in[4];
  const float* WO  = (const float*)d_in[5];

  char* ws = (char*)d_ws;
  u16* xb  = (u16*)(ws);                          // 8 MB  x bf16 [4096][1024]
  u16* wqb = (u16*)(ws + (size_t)(8)  * 1048576);
  u16* wkb = (u16*)(ws + (size_t)(10) * 1048576);
  u16* wvb = (u16*)(ws + (size_t)(12) * 1048576);
  u16* wob = (u16*)(ws + (size_t)(14) * 1048576);
  u16* Yq  = (u16*)(ws + (size_t)(16) * 1048576); // 8 MB each
  u16* Yk  = (u16*)(ws + (size_t)(24) * 1048576);
  u16* Yv  = (u16*)(ws + (size_t)(32) * 1048576);
  u16* Qb  = (u16*)(ws + (size_t)(40) * 1048576); // [B,H,S,dk]
  u16* Kb  = (u16*)(ws + (size_t)(48) * 1048576);
  u16* Vt  = (u16*)(ws + (size_t)(56) * 1048576); // [B,H,dk,S]
  u16* Ob  = (u16*)(ws + (size_t)(64) * 1048576); // [B,S,H,dk]

  // 1. convert inputs to bf16 (single launch)
  cvt_all<<<dim3(1024, 8), 256, 0, stream>>>(x, WQ, WK, WV, WO, xb, wqb, wkb, wvb, wob);

  // 2. Q/K/V projections (batched over grid.z)
  gemm_bt<<<dim3(D_MODEL / BN, BS_ROWS / BM, 3), 256, 0, stream>>>(
      xb, wqb, wkb, wvb, Yq, Yk, Yv, nullptr, BS_ROWS, D_MODEL, D_MODEL, 0);

  // 3a. RoPE on Q,K
  rope_pack<<<(BS_ROWS * (D_MODEL / 2)) / 256, 256, 0, stream>>>(
      Yq, Yk, pos, Qb, Kb);

  // 3b. V transpose via LDS tiles (coalesced both sides)
  transpose_v<<<dim3(S_LEN / 64, BATCH * NH), 256, 0, stream>>>(Yv, Vt);

  // 4. causal flash attention (unpaired, longest-first)
  attn_fwd<<<dim3(1024), 256, 0, stream>>>(Qb, Kb, Vt, Ob);

  // 5. output projection -> fp32 d_out
  gemm_bt<<<dim3(D_MODEL / BN, BS_ROWS / BM, 1), 256, 0, stream>>>(
      Ob, wob, wob, wob, nullptr, nullptr, nullptr, (float*)d_out,
      BS_ROWS, D_MODEL, D_MODEL, 1);
}

// Round 7
// 226.938 us; speedup vs baseline: 1.2737x; 1.0496x over previous
//
#include <hip/hip_runtime.h>
#include <hip/hip_bf16.h>

// Problem constants (B=2, S=2048, D=1024, H=16, dk=64)
#define S_LEN   2048
#define D_MODEL 1024
#define NH      16
#define DKH     64
#define BATCH   2
#define BS_ROWS 4096   // B*S

typedef unsigned short u16;
typedef unsigned int   u32;
typedef __attribute__((ext_vector_type(4)))  float f32x4;
typedef __attribute__((ext_vector_type(16))) float f32x16;
typedef __attribute__((ext_vector_type(8)))  short bf16x8;

__device__ __forceinline__ float bf2f(u16 u) {
  union { unsigned int i; float f; } v; v.i = ((unsigned int)u) << 16; return v.f;
}
__device__ __forceinline__ u16 f2bf(float f) {
  union { __hip_bfloat16 h; u16 u; } cv; cv.h = __float2bfloat16(f); return cv.u;
}
__device__ __forceinline__ u32 pkbf(float a, float b) {
  return (u32)f2bf(a) | ((u32)f2bf(b) << 16);
}
__device__ __forceinline__ f32x4 mfma16(bf16x8 a, bf16x8 b, f32x4 c) {
  return __builtin_amdgcn_mfma_f32_16x16x32_bf16(a, b, c, 0, 0, 0);
}
__device__ __forceinline__ f32x16 mfma32(bf16x8 a, bf16x8 b, f32x16 c) {
  return __builtin_amdgcn_mfma_f32_32x32x16_bf16(a, b, c, 0, 0, 0);
}
// async global->LDS, 16B per lane. LDS ptr wave-uniform; HW adds lane*16.
__device__ __forceinline__ void gl_lds16(const u16* g, u16* l) {
  __builtin_amdgcn_global_load_lds(
      (const __attribute__((address_space(1))) void*)g,
      (__attribute__((address_space(3))) void*)l, 16, 0, 0);
}

// ---------------- fp32 -> bf16 convert (single launch, 8 segments) ----------------
__global__ void cvt_all(const float* __restrict__ x,
                        const float* __restrict__ wq, const float* __restrict__ wk,
                        const float* __restrict__ wv, const float* __restrict__ wo,
                        u16* __restrict__ xb, u16* __restrict__ wqb, u16* __restrict__ wkb,
                        u16* __restrict__ wvb, u16* __restrict__ wob) {
  int seg = blockIdx.y;
  const float* src; u16* dst;
  if (seg < 4)      { src = x + (size_t)seg * (1u << 20); dst = xb + (size_t)seg * (1u << 20); }
  else if (seg == 4){ src = wq; dst = wqb; }
  else if (seg == 5){ src = wk; dst = wkb; }
  else if (seg == 6){ src = wv; dst = wvb; }
  else              { src = wo; dst = wob; }
  int i = blockIdx.x * 256 + threadIdx.x;      // 262144 float4 per segment
  float4 v = reinterpret_cast<const float4*>(src)[i];
  ushort4 o;
  o.x = f2bf(v.x); o.y = f2bf(v.y); o.z = f2bf(v.z); o.w = f2bf(v.w);
  reinterpret_cast<ushort4*>(dst)[i] = o;
}

// ---------------- GEMM  C[m,n] = sum_k A[m,k]*B[n,k]  (B^T layout) ----------------
#define BM 128
#define BN 128
#define BKK 64

__global__ __launch_bounds__(256) void gemm_bt(
    const u16* __restrict__ A,
    const u16* __restrict__ B0, const u16* __restrict__ B1, const u16* __restrict__ B2,
    u16* __restrict__ C0, u16* __restrict__ C1, u16* __restrict__ C2,
    float* __restrict__ Cf,
    int M, int N, int K, int out_f32)
{
  __shared__ __align__(16) u16 As[BM * BKK];
  __shared__ __align__(16) u16 Bs[BN * BKK];

  const int z = blockIdx.z;
  const u16* Bm = (z == 0) ? B0 : ((z == 1) ? B1 : B2);
  u16* Cb = (z == 0) ? C0 : ((z == 1) ? C1 : C2);

  const int tid = threadIdx.x;
  const int l = tid & 63, w = tid >> 6;
  const int lr = l & 15, lg = l >> 4;
  const int m0 = blockIdx.y * BM, n0 = blockIdx.x * BN;
  const int wr = w >> 1, wc = w & 1;

  f32x4 acc[4][4];
#pragma unroll
  for (int mi = 0; mi < 4; ++mi)
#pragma unroll
    for (int nj = 0; nj < 4; ++nj)
      acc[mi][nj] = (f32x4){0.f, 0.f, 0.f, 0.f};

  for (int k0 = 0; k0 < K; k0 += BKK) {
    __syncthreads();
#pragma unroll
    for (int i = 0; i < 4; ++i) {
      int Dc = w * 256 + i * 64 + l;        // dest chunk (linear in LDS)
      int row = Dc >> 3;                    // 8 chunks per 128B row
      int c = (Dc & 7) ^ (row & 7);         // pre-swizzled source chunk
      gl_lds16(A  + (size_t)(m0 + row) * K + k0 + c * 8, As + (w * 256 + i * 64) * 8);
      gl_lds16(Bm + (size_t)(n0 + row) * K + k0 + c * 8, Bs + (w * 256 + i * 64) * 8);
    }
    __syncthreads();

    bf16x8 af[2][4], bfr[2][4];
#pragma unroll
    for (int kk = 0; kk < 2; ++kk)
#pragma unroll
      for (int mi = 0; mi < 4; ++mi) {
        int rowa = wr * 64 + mi * 16 + lr;
        int ck = kk * 4 + lg;
        af[kk][mi] = *(const bf16x8*)&As[rowa * BKK + (((ck) ^ (rowa & 7)) << 3)];
        int rowb = wc * 64 + mi * 16 + lr;
        bfr[kk][mi] = *(const bf16x8*)&Bs[rowb * BKK + (((ck) ^ (rowb & 7)) << 3)];
      }
#pragma unroll
    for (int kk = 0; kk < 2; ++kk)
#pragma unroll
      for (int mi = 0; mi < 4; ++mi)
#pragma unroll
        for (int nj = 0; nj < 4; ++nj)
          acc[mi][nj] = mfma16(af[kk][mi], bfr[kk][nj], acc[mi][nj]);
  }

  // epilogue: C/D layout col=lane&15, row=(lane>>4)*4+reg
#pragma unroll
  for (int mi = 0; mi < 4; ++mi)
#pragma unroll
    for (int nj = 0; nj < 4; ++nj)
#pragma unroll
      for (int r = 0; r < 4; ++r) {
        int row = m0 + wr * 64 + mi * 16 + lg * 4 + r;
        int col = n0 + wc * 64 + nj * 16 + lr;
        float v = acc[mi][nj][r];
        if (out_f32) Cf[(size_t)row * N + col] = v;
        else         Cb[(size_t)row * N + col] = f2bf(v);
      }
}

// ---------------- RoPE (Q,K only) ----------------
// Q gets 0.125 * log2(e) folded in (softmax runs in exp2 domain).
__global__ void rope_pack(const u16* __restrict__ Yq, const u16* __restrict__ Yk,
                          const int* __restrict__ pos,
                          u16* __restrict__ Qb, u16* __restrict__ Kb)
{
  int t = blockIdx.x * blockDim.x + threadIdx.x;  // one thread per (row, pair)
  if (t >= BS_ROWS * (D_MODEL / 2)) return;
  int pi = t & 511;            // pair index in row: h*32 + j
  int r  = t >> 9;             // row = b*S + s
  int h = pi >> 5, j = pi & 31;
  int b = r >> 11, s = r & (S_LEN - 1);
  int p = pos[s];

  float freq = exp2f(-(float)j * 0.41524101186092028f);  // log2(10000)/32
  float ang = (float)p * freq;
  float sn, cs;
  sincosf(ang, &sn, &cs);

  int base = r * D_MODEL + pi * 2;
  float q0 = bf2f(Yq[base]), q1 = bf2f(Yq[base + 1]);
  float k0 = bf2f(Yk[base]), k1 = bf2f(Yk[base + 1]);

  const float QS = 0.18033688011112042f;  // 0.125 * log2(e)
  float qr0 = (cs * q0 - sn * q1) * QS;
  float qr1 = (sn * q0 + cs * q1) * QS;
  float kr0 = cs * k0 - sn * k1;
  float kr1 = sn * k0 + cs * k1;

  int bh = b * NH + h;
  size_t qidx = ((size_t)bh * S_LEN + s) * DKH + 2 * j;
  ushort2 qo; qo.x = f2bf(qr0); qo.y = f2bf(qr1);
  ushort2 ko; ko.x = f2bf(kr0); ko.y = f2bf(kr1);
  *reinterpret_cast<ushort2*>(Qb + qidx) = qo;
  *reinterpret_cast<ushort2*>(Kb + qidx) = ko;
}

// ---------------- V transpose:  Vt[bh][d][s] = Yv[b*S+s][h*64+d] ----------------
__global__ __launch_bounds__(256) void transpose_v(const u16* __restrict__ Yv,
                                                   u16* __restrict__ Vt)
{
  __shared__ u32 T[64][65];
  const int sb = blockIdx.x;            // s-tile (0..31)
  const int bh = blockIdx.y;            // 0..31
  const int b = bh >> 4, h = bh & 15;
  const int t = threadIdx.x;
  const int s0 = sb * 64;

#pragma unroll
  for (int pass = 0; pass < 2; ++pass) {
    int row = pass * 32 + (t >> 3);     // 0..63
    int c0 = (t & 7) * 8;
    bf16x8 v = *(const bf16x8*)(Yv + (size_t)(b * S_LEN + s0 + row) * D_MODEL + h * DKH + c0);
#pragma unroll
    for (int i = 0; i < 8; ++i) T[row][c0 + i] = (u32)(u16)v[i];
  }
  __syncthreads();

  const int d = t >> 2, ch = t & 3;
  bf16x8 o0, o1;
#pragma unroll
  for (int i = 0; i < 8; ++i) o0[i] = (short)(u16)T[ch * 16 + i][d];
#pragma unroll
  for (int i = 0; i < 8; ++i) o1[i] = (short)(u16)T[ch * 16 + 8 + i][d];
  u16* dst = Vt + ((size_t)bh * DKH + d) * S_LEN + s0 + ch * 16;
  *(bf16x8*)dst = o0;
  *(bf16x8*)(dst + 8) = o1;
}

// ---------------- causal flash attention (swapped-QK, 32x32 MFMA) ----------------
// 512 blocks: blocks c and c+256 get qt p and 15-p -> 34 tiles per CU uniformly.
// Wave w owns 32 q-rows. mfma(K,Q) puts S^T lane-local: lane l holds q-col l&31,
// kv rows (reg&3)+8*(reg>>2)+4*(l>>5) per 32-kv sub. Softmax fully in-register;
// P->PV A-frag via pack + one shfl_xor(32) exchange (no P-LDS round trip).
__global__ __launch_bounds__(256, 2) void attn_fwd(
    const u16* __restrict__ Qb, const u16* __restrict__ Kb,
    const u16* __restrict__ Vt, u16* __restrict__ Ob)
{
  const int f = blockIdx.x;
  const int qt = (f < 256) ? (f >> 5) : (23 - (f >> 5));  // pair sums to 15
  const int bh = f & 31;                                  // bh%8 = f%8 -> fixed XCD
  const int b = bh >> 4, h = bh & 15;
  const int tid = threadIdx.x, l = tid & 63, w = tid >> 6;
  const int lq = l & 31;          // q-col owner / kv-row / d-col index
  const int hi = l >> 5;

  __shared__ __align__(16) u16 Ks[2][64 * 64];
  __shared__ __align__(16) u16 Vs[2][64 * 64];

  const u16* Qh = Qb + (size_t)bh * S_LEN * DKH;
  const u16* Kh = Kb + (size_t)bh * S_LEN * DKH;
  const u16* Vh = Vt + (size_t)bh * DKH * S_LEN;

  const int q0w = qt * 128 + w * 32;
  const int qg  = q0w + lq;

  // Q fragments: B-operand, lane l = Q[q0w+lq][ks*16 + hi*8 .. +8]
  bf16x8 qf[4];
#pragma unroll
  for (int ks = 0; ks < 4; ++ks)
    qf[ks] = *(const bf16x8*)(Qh + (size_t)qg * DKH + ks * 16 + hi * 8);

  f32x16 oacc[2];
#pragma unroll
  for (int r = 0; r < 16; ++r) { oacc[0][r] = 0.f; oacc[1][r] = 0.f; }
  float m = -INFINITY, lsum = 0.f;

#define STAGE(buf, tt) do {                                                        \
    int kv0s = (tt) * 64;                                                          \
    _Pragma("unroll")                                                              \
    for (int i = 0; i < 2; ++i) {                                                  \
      int Dc = w * 128 + i * 64 + l;                                               \
      int row = Dc >> 3;                                                           \
      int c = (Dc & 7) ^ (row & 7);                                                \
      gl_lds16(Kh + (size_t)(kv0s + row) * DKH + c * 8, &Ks[buf][(w * 128 + i * 64) * 8]); \
      gl_lds16(Vh + (size_t)row * S_LEN + kv0s + c * 8, &Vs[buf][(w * 128 + i * 64) * 8]); \
    }                                                                              \
  } while (0)

  const int nt = 2 * qt + 2;
  STAGE(0, 0);
  __syncthreads();
  int cur = 0;
  for (int t = 0; t < nt; ++t) {
    if (t + 1 < nt) STAGE(cur ^ 1, t + 1);
    const int kv0 = t * 64;
    if (kv0 <= q0w + 31) {                 // wave-active (not fully causal-masked)
      // S^T = mfma(K, Q): two kv-subs of 32
      f32x16 sv0, sv1;
#pragma unroll
      for (int r = 0; r < 16; ++r) { sv0[r] = 0.f; sv1[r] = 0.f; }
#pragma unroll
      for (int ks = 0; ks < 4; ++ks) {
        int c0 = ((ks * 2 + hi) ^ (l & 7)) << 3;
        bf16x8 k0 = *(const bf16x8*)&Ks[cur][lq * 64 + c0];
        bf16x8 k1 = *(const bf16x8*)&Ks[cur][(32 + lq) * 64 + c0];
        sv0 = mfma32(k0, qf[ks], sv0);
        sv1 = mfma32(k1, qf[ks], sv1);
      }
      // causal mask (diag region only)
      if (kv0 + 63 > q0w) {
#pragma unroll
        for (int r = 0; r < 16; ++r) {
          int kvl = (r & 3) + 8 * (r >> 2) + 4 * hi;
          if (kv0 + kvl > qg)      sv0[r] = -1e30f;
          if (kv0 + 32 + kvl > qg) sv1[r] = -1e30f;
        }
      }
      // row max: in-register + one cross-half exchange
      float pm = sv0[0];
#pragma unroll
      for (int r = 1; r < 16; ++r) pm = fmaxf(pm, sv0[r]);
#pragma unroll
      for (int r = 0; r < 16; ++r) pm = fmaxf(pm, sv1[r]);
      pm = fmaxf(pm, __shfl_xor(pm, 32));
      // defer-max (log2 domain, THR=8)
      if (__any(pm > m + 8.f)) {
        float mn = fmaxf(m, pm);
        float sc = exp2f(m - mn);
        m = mn; lsum *= sc;
#pragma unroll
        for (int r = 0; r < 16; ++r) {
          float sr = __shfl(sc, (r & 3) + 8 * (r >> 2) + 4 * hi);
          oacc[0][r] *= sr; oacc[1][r] *= sr;
        }
      }
      float ps = 0.f;
#pragma unroll
      for (int r = 0; r < 16; ++r) { float p = exp2f(sv0[r] - m); sv0[r] = p; ps += p; }
#pragma unroll
      for (int r = 0; r < 16; ++r) { float p = exp2f(sv1[r] - m); sv1[r] = p; ps += p; }
      lsum += ps;
      // PV: build P A-frags (pack + one shfl_xor(32)), mfma with V from LDS
#pragma unroll
      for (int s = 0; s < 2; ++s) {
        u32 w0[4], w1[4];
#pragma unroll
        for (int g = 0; g < 4; ++g) {
          float a0 = s ? sv1[4 * g]     : sv0[4 * g];
          float a1 = s ? sv1[4 * g + 1] : sv0[4 * g + 1];
          float a2 = s ? sv1[4 * g + 2] : sv0[4 * g + 2];
          float a3 = s ? sv1[4 * g + 3] : sv0[4 * g + 3];
          w0[g] = pkbf(a0, a1);
          w1[g] = pkbf(a2, a3);
        }
#pragma unroll
        for (int t2 = 0; t2 < 2; ++t2) {
          u32 xo0 = hi ? w0[2 * t2 + 1] : w0[2 * t2];
          u32 xo1 = hi ? w1[2 * t2 + 1] : w1[2 * t2];
          u32 sp0 = hi ? w0[2 * t2]     : w0[2 * t2 + 1];
          u32 sp1 = hi ? w1[2 * t2]     : w1[2 * t2 + 1];
          u32 yo0 = __shfl_xor(sp0, 32);
          u32 yo1 = __shfl_xor(sp1, 32);
          union { u32 u[4]; bf16x8 v; } pa;
          pa.u[0] = hi ? yo0 : xo0;
          pa.u[1] = hi ? yo1 : xo1;
          pa.u[2] = hi ? xo0 : yo0;
          pa.u[3] = hi ? xo1 : yo1;
          int ks2 = s * 2 + t2;
          int cv = ((ks2 * 2 + hi) ^ (l & 7)) << 3;
#pragma unroll
          for (int dh = 0; dh < 2; ++dh) {
            bf16x8 vf = *(const bf16x8*)&Vs[cur][(dh * 32 + lq) * 64 + cv];
            oacc[dh] = mfma32(pa.v, vf, oacc[dh]);
          }
        }
      }
    }
    __syncthreads();             // drains prefetch vmcnt + buffer swap
    cur ^= 1;
  }
#undef STAGE

  // finalize: combine lsum halves, broadcast inv to O's reg-row layout, store
  float ltot = lsum + __shfl_xor(lsum, 32);
  float inv = 1.0f / ltot;
  u16* obase = Ob + (size_t)b * S_LEN * D_MODEL + (size_t)h * DKH;
#pragma unroll
  for (int r = 0; r < 16; ++r) {
    int ql = (r & 3) + 8 * (r >> 2) + 4 * hi;
    float ir = __shfl(inv, ql);
    u16* orow = obase + (size_t)(q0w + ql) * D_MODEL;
    orow[lq]      = f2bf(oacc[0][r] * ir);
    orow[32 + lq] = f2bf(oacc[1][r] * ir);
  }
}

// ---------------- launch ----------------
extern "C" void kernel_launch(void* const* d_in, const int* in_sizes, int n_in,
                              void* d_out, int out_size, void* d_ws, size_t ws_size,
                              hipStream_t stream) {
  const float* x   = (const float*)d_in[0];
  const int*   pos = (const int*)d_in[1];
  const float* WQ  = (const float*)d_in[2];
  const float* WK  = (const float*)d_in[3];
  const float* WV  = (const float*)d_in[4];
  const float* WO  = (const float*)d_in[5];

  char* ws = (char*)d_ws;
  u16* xb  = (u16*)(ws);                          // 8 MB  x bf16 [4096][1024]
  u16* wqb = (u16*)(ws + (size_t)(8)  * 1048576);
  u16* wkb = (u16*)(ws + (size_t)(10) * 1048576);
  u16* wvb = (u16*)(ws + (size_t)(12) * 1048576);
  u16* wob = (u16*)(ws + (size_t)(14) * 1048576);
  u16* Yq  = (u16*)(ws + (size_t)(16) * 1048576); // 8 MB each
  u16* Yk  = (u16*)(ws + (size_t)(24) * 1048576);
  u16* Yv  = (u16*)(ws + (size_t)(32) * 1048576);
  u16* Qb  = (u16*)(ws + (size_t)(40) * 1048576); // [B,H,S,dk]
  u16* Kb  = (u16*)(ws + (size_t)(48) * 1048576);
  u16* Vt  = (u16*)(ws + (size_t)(56) * 1048576); // [B,H,dk,S]
  u16* Ob  = (u16*)(ws + (size_t)(64) * 1048576); // [B,S,H,dk]

  // 1. convert inputs to bf16 (single launch)
  cvt_all<<<dim3(1024, 8), 256, 0, stream>>>(x, WQ, WK, WV, WO, xb, wqb, wkb, wvb, wob);

  // 2. Q/K/V projections (batched over grid.z)
  gemm_bt<<<dim3(D_MODEL / BN, BS_ROWS / BM, 3), 256, 0, stream>>>(
      xb, wqb, wkb, wvb, Yq, Yk, Yv, nullptr, BS_ROWS, D_MODEL, D_MODEL, 0);

  // 3a. RoPE on Q,K
  rope_pack<<<(BS_ROWS * (D_MODEL / 2)) / 256, 256, 0, stream>>>(
      Yq, Yk, pos, Qb, Kb);

  // 3b. V transpose via LDS tiles (coalesced both sides)
  transpose_v<<<dim3(S_LEN / 64, BATCH * NH), 256, 0, stream>>>(Yv, Vt);

  // 4. causal flash attention (swapped-QK, 32x32 MFMA)
  attn_fwd<<<dim3(512), 256, 0, stream>>>(Qb, Kb, Vt, Ob);

  // 5. output projection -> fp32 d_out
  gemm_bt<<<dim3(D_MODEL / BN, BS_ROWS / BM, 1), 256, 0, stream>>>(
      Ob, wob, wob, wob, nullptr, nullptr, nullptr, (float*)d_out,
      BS_ROWS, D_MODEL, D_MODEL, 1);
}